// Round 1
// baseline (352.962 us; speedup 1.0000x reference)
//
#include <hip/hip_runtime.h>

#define DIM   256
#define BATCH 16
#define KS    7
#define PAD   3
#define NKER  15
#define STEPS 32

// output tile per block
#define TX 32
#define TY 8
#define HX (TX + 2*PAD)   // 38
#define HY (TY + 2*PAD)   // 14

// Collapse the 14 used fd_kernels into one effective 7x7 kernel.
// eff[t] = sum_{c=1..14} fd_kernels[c,0,t] * combo_w[0,c-1,0,0]
__global__ void prep_eff(const float* __restrict__ fdk,
                         const float* __restrict__ cw,
                         float* __restrict__ eff) {
    int t = threadIdx.x;
    if (t < KS * KS) {
        float s = 0.f;
        #pragma unroll
        for (int c = 1; c < NKER; ++c)
            s += fdk[c * KS * KS + t] * cw[c - 1];
        eff[t] = s;
    }
}

// One FDTD step:
// u2 = (conv7x7(u1,eff) + 8*epsr*u1 - (4*epsr - sigma)*u0 + src_delta) / (4*epsr + sigma)
__global__ __launch_bounds__(256) void step_kernel(
    const float* __restrict__ u1c,    // [B,DIM,DIM] current field
    const float* __restrict__ u0c,    // [B,DIM,DIM] previous field (pointwise only)
    const float* __restrict__ epsr,
    const float* __restrict__ sigma,
    const float* __restrict__ eff,    // 49 taps (uniform -> s_load)
    const float* __restrict__ src,    // [STEPS,2]
    float* __restrict__ u2,
    int s)
{
    __shared__ float tile[HY][HX];    // 38-stride: wave64 reads 2 rows -> 2 lanes/bank, free

    const int t  = threadIdx.x;
    const int x0 = blockIdx.x * TX;
    const int y0 = blockIdx.y * TY;
    const int b  = blockIdx.z;
    const float* u1b = u1c + (size_t)b * DIM * DIM;

    // cooperative halo load (HY*HX = 532 elements, 256 threads)
    for (int i = t; i < HX * HY; i += 256) {
        int hy = i / HX, hx = i - hy * HX;
        int gy = y0 + hy - PAD;
        int gx = x0 + hx - PAD;
        float v = 0.f;
        if (gy >= 0 && gy < DIM && gx >= 0 && gx < DIM)
            v = u1b[gy * DIM + gx];
        tile[hy][hx] = v;
    }
    __syncthreads();

    const int lx = t & (TX - 1);
    const int ly = t >> 5;            // t / TX
    const int gx = x0 + lx;
    const int gy = y0 + ly;

    float combo = 0.f;
    #pragma unroll
    for (int kh = 0; kh < KS; ++kh) {
        #pragma unroll
        for (int kw = 0; kw < KS; ++kw) {
            combo = fmaf(tile[ly + kh][lx + kw], eff[kh * KS + kw], combo);
        }
    }

    const size_t idx = (size_t)b * DIM * DIM + (size_t)gy * DIM + gx;
    const float e   = epsr[idx];
    const float sg  = sigma[idx];
    const float u1v = tile[ly + PAD][lx + PAD];
    const float u0v = u0c[idx];

    float rhs = combo + 8.f * e * u1v - (4.f * e - sg) * u0v;
    if (gy == 128 && gx == 128)
        rhs += -(src[2 * s] - src[2 * s + 1]);   // source injection at (CX,CY)

    u2[idx] = rhs / (4.f * e + sg);
}

extern "C" void kernel_launch(void* const* d_in, const int* in_sizes, int n_in,
                              void* d_out, int out_size, void* d_ws, size_t ws_size,
                              hipStream_t stream) {
    (void)in_sizes; (void)n_in; (void)out_size; (void)ws_size;

    const float* u1    = (const float*)d_in[0];
    const float* u0    = (const float*)d_in[1];
    const float* epsr  = (const float*)d_in[2];
    const float* sigma = (const float*)d_in[3];
    const float* fdk   = (const float*)d_in[4];
    const float* cw    = (const float*)d_in[5];
    const float* src   = (const float*)d_in[6];
    // d_in[7] = stepnum (always 32)

    float* eff  = (float*)d_ws;                         // 49 floats (pad to 64)
    float* bufA = (float*)((char*)d_ws + 256);
    float* bufB = bufA + (size_t)BATCH * DIM * DIM;
    float* out  = (float*)d_out;

    prep_eff<<<1, 64, 0, stream>>>(fdk, cw, eff);

    dim3 grid(DIM / TX, DIM / TY, BATCH);   // (8, 32, 16)

    const float* pu0 = u0;   // previous field
    const float* pu1 = u1;   // current field
    for (int s = 0; s < STEPS; ++s) {
        float* o;
        if (s == STEPS - 1)      o = out;
        else if (s == 0)         o = bufA;
        else if (s == 1)         o = bufB;
        else                     o = (float*)pu0;  // retiring ws buffer; u0 is read
                                                   // only pointwise by the writing
                                                   // thread -> in-place is safe
        step_kernel<<<grid, 256, 0, stream>>>(pu1, pu0, epsr, sigma, eff, src, o, s);
        pu0 = pu1;
        pu1 = o;
    }
}